// Round 2
// baseline (9.658 us; speedup 1.0000x reference)
//
#include <hip/hip_runtime.h>
#include <hip/hip_bf16.h>

// CTPN loss: 4 scalar outputs (loss, cls_loss, v_reg_loss, o_reg_loss).
// Shapes: score/vertical_pred [1,20,512,768] f32, side_refinement [1,10,512,768] f32.
// NP=NN=NO=64, NV=128, NS=128.
//
// Structure: one block, 5 waves, one sub-task per wave:
//   wave 0: pos cls   wave 1: neg cls   waves 2-3: vertical   wave 4: side
// Each thread holds exactly ONE partial -> single wave-reduce + LDS combine.

#define HH 512
#define WW 768
#define HW (HH * WW)

__device__ __forceinline__ float smooth_l1(float d) {
    float a = fabsf(d);
    return (a < 1.0f) ? 0.5f * d * d : a - 0.5f;
}

__device__ __forceinline__ float wave_reduce_sum(float v) {
    #pragma unroll
    for (int off = 32; off > 0; off >>= 1)
        v += __shfl_down(v, off, 64);
    return v;
}

// stable -log_softmax residual: lse(c0,c1) computed with native exp2/log2
__device__ __forceinline__ float lse2(float c0, float c1) {
    float m = fmaxf(c0, c1);
    // __expf/__logf lower to v_exp_f32/v_log_f32 (base-2 HW ops + scale)
    return m + __logf(__expf(c0 - m) + __expf(c1 - m));
}

__global__ __launch_bounds__(320) void ctpn_loss_kernel(
    const float* __restrict__ score,
    const float* __restrict__ vpred,
    const float* __restrict__ side,
    const int* __restrict__ px, const int* __restrict__ py, const int* __restrict__ pa,
    const int* __restrict__ nx, const int* __restrict__ ny, const int* __restrict__ na,
    const int* __restrict__ vx, const int* __restrict__ vy, const int* __restrict__ va,
    const float* __restrict__ vt,
    const int* __restrict__ ox, const int* __restrict__ oy, const int* __restrict__ oa,
    const float* __restrict__ ot,
    float* __restrict__ out)
{
    const int tid  = threadIdx.x;
    const int wid  = tid >> 6;      // 0..4
    const int lane = tid & 63;

    float part = 0.0f;

    if (wid == 0) {
        // positive classification: lse - c1
        int x = px[lane], y = py[lane], a = pa[lane];
        const float* base = score + (size_t)(a * 2) * HW + (size_t)y * WW + x;
        float c0 = base[0], c1 = base[HW];
        part = lse2(c0, c1) - c1;
    } else if (wid == 1) {
        // negative classification: lse - c0
        int x = nx[lane], y = ny[lane], a = na[lane];
        const float* base = score + (size_t)(a * 2) * HW + (size_t)y * WW + x;
        float c0 = base[0], c1 = base[HW];
        part = lse2(c0, c1) - c0;
    } else if (wid < 4) {
        // vertical regression (128 samples on waves 2-3)
        int i = tid - 128;
        int x = vx[i], y = vy[i], a = va[i];
        const float* base = vpred + (size_t)(a * 2) * HW + (size_t)y * WW + x;
        float p0 = base[0], p1 = base[HW];
        part = smooth_l1(p0 - vt[2 * i]) + smooth_l1(p1 - vt[2 * i + 1]);
    } else {
        // side refinement (64 samples on wave 4)
        int x = ox[lane], y = oy[lane], a = oa[lane];
        float p = side[(size_t)a * HW + (size_t)y * WW + x];
        part = smooth_l1(p - ot[lane]);
    }

    float wsum = wave_reduce_sum(part);

    __shared__ float s[5];
    if (lane == 0) s[wid] = wsum;
    __syncthreads();

    if (tid == 0) {
        float cls_loss = (s[0] + s[1]) / 128.0f;   // NS = 128
        float v_reg    = (s[2] + s[3]) / 256.0f;   // NV * 2 elements
        float o_reg    =  s[4]         / 64.0f;    // NO
        out[0] = cls_loss + v_reg + o_reg;         // LAMBDA1 = LAMBDA2 = 1
        out[1] = cls_loss;
        out[2] = v_reg;
        out[3] = o_reg;
    }
}

extern "C" void kernel_launch(void* const* d_in, const int* in_sizes, int n_in,
                              void* d_out, int out_size, void* d_ws, size_t ws_size,
                              hipStream_t stream) {
    const float* score = (const float*)d_in[0];
    const float* vpred = (const float*)d_in[1];
    const float* side  = (const float*)d_in[2];
    const int* px = (const int*)d_in[3];
    const int* py = (const int*)d_in[4];
    const int* pa = (const int*)d_in[5];
    const int* nx = (const int*)d_in[6];
    const int* ny = (const int*)d_in[7];
    const int* na = (const int*)d_in[8];
    const int* vx = (const int*)d_in[9];
    const int* vy = (const int*)d_in[10];
    const int* va = (const int*)d_in[11];
    const float* vt = (const float*)d_in[12];
    const int* ox = (const int*)d_in[13];
    const int* oy = (const int*)d_in[14];
    const int* oa = (const int*)d_in[15];
    const float* ot = (const float*)d_in[16];
    float* out = (float*)d_out;

    ctpn_loss_kernel<<<1, 320, 0, stream>>>(
        score, vpred, side,
        px, py, pa, nx, ny, na,
        vx, vy, va, vt,
        ox, oy, oa, ot,
        out);
}